// Round 1
// baseline (7439.054 us; speedup 1.0000x reference)
//
#include <hip/hip_runtime.h>

#define N_IN   128
#define HID    32
#define ODIM   12

__device__ __forceinline__ void atomAddF(float* p, float v) {
    unsafeAtomicAdd(p, v);   // HW global_atomic_add_f32 (no CAS loop)
}

// h1[n][32] = feat[n][0:128] @ W1.  64 nodes/block, thread = 2 nodes x 4 outs.
__global__ __launch_bounds__(256) void gemm1_kernel(const float* __restrict__ feat,
                                                    const float* __restrict__ W1,
                                                    float* __restrict__ h1, int nNodes) {
    __shared__ float sF[64 * 132];     // 64 rows x 128 cols (+4 pad) -> conflict-free
    __shared__ float sW[N_IN * HID];   // 128 x 32
    const int tid = threadIdx.x;
    const int nb  = blockIdx.x * 64;

    // stage W1: 4096 floats = 1024 float4, 4/thread
    {
        const float4* Wv  = (const float4*)W1;
        float4*       sWv = (float4*)sW;
        #pragma unroll
        for (int i = 0; i < 4; ++i) sWv[tid + 256 * i] = Wv[tid + 256 * i];
    }
    // stage feat tile: 64 rows x 128 = 2048 float4, 8/thread, coalesced per row
    #pragma unroll
    for (int i = 0; i < 8; ++i) {
        int f   = tid + 256 * i;        // 0..2047
        int row = f >> 5;               // 32 float4 per row
        int c4  = f & 31;
        int n   = nb + row;
        float4 v = make_float4(0.f, 0.f, 0.f, 0.f);
        if (n < nNodes) v = *(const float4*)(feat + (size_t)n * N_IN + c4 * 4);
        *(float4*)(sF + row * 132 + c4 * 4) = v;
    }
    __syncthreads();

    const int og = tid & 7;             // 8 out-groups of 4
    const int ng = tid >> 3;            // 32 node-groups
    const int o0 = og * 4;
    const float* f0 = sF + ng * 132;
    const float* f1 = sF + (ng + 32) * 132;

    float acc0[4] = {0.f, 0.f, 0.f, 0.f};
    float acc1[4] = {0.f, 0.f, 0.f, 0.f};
    #pragma unroll 8
    for (int k = 0; k < N_IN; k += 4) {
        float4 a0 = *(const float4*)(f0 + k);
        float4 a1 = *(const float4*)(f1 + k);
        const float a0v[4] = {a0.x, a0.y, a0.z, a0.w};
        const float a1v[4] = {a1.x, a1.y, a1.z, a1.w};
        #pragma unroll
        for (int j = 0; j < 4; ++j) {
            float4 w = *(const float4*)(sW + (k + j) * HID + o0);
            acc0[0] += a0v[j] * w.x; acc0[1] += a0v[j] * w.y;
            acc0[2] += a0v[j] * w.z; acc0[3] += a0v[j] * w.w;
            acc1[0] += a1v[j] * w.x; acc1[1] += a1v[j] * w.y;
            acc1[2] += a1v[j] * w.z; acc1[3] += a1v[j] * w.w;
        }
    }
    int n0 = nb + ng, n1 = nb + ng + 32;
    if (n0 < nNodes) *(float4*)(h1 + (size_t)n0 * HID + o0) = make_float4(acc0[0], acc0[1], acc0[2], acc0[3]);
    if (n1 < nNodes) *(float4*)(h1 + (size_t)n1 * HID + o0) = make_float4(acc1[0], acc1[1], acc1[2], acc1[3]);
}

// agg1[dst] += h1[src]; deg[dst] += 1.  One thread per edge.
__global__ __launch_bounds__(256) void scatter1_kernel(const float* __restrict__ h1,
                                                       const int* __restrict__ src,
                                                       const int* __restrict__ dst,
                                                       float* __restrict__ agg1,
                                                       float* __restrict__ deg, int nEdges) {
    int e = blockIdx.x * 256 + threadIdx.x;
    if (e >= nEdges) return;
    int s = src[e], d = dst[e];
    atomAddF(deg + d, 1.0f);
    const float4* hr = (const float4*)(h1 + (size_t)s * HID);
    float*        ar = agg1 + (size_t)d * HID;
    #pragma unroll
    for (int i = 0; i < 8; ++i) {
        float4 v = hr[i];
        atomAddF(ar + i * 4 + 0, v.x);
        atomAddF(ar + i * 4 + 1, v.y);
        atomAddF(ar + i * 4 + 2, v.z);
        atomAddF(ar + i * 4 + 3, v.w);
    }
}

// x = relu(agg1/deg + b1)  (extra relu idempotent), then h2[n][12] = x[n] @ W2
// block = 8 nodes x 32 lanes
__global__ __launch_bounds__(256) void fin1_gemm2_kernel(const float* __restrict__ agg1,
                                                         const float* __restrict__ deg,
                                                         const float* __restrict__ b1,
                                                         const float* __restrict__ W2,
                                                         float* __restrict__ h2, int nNodes) {
    __shared__ float sX[8][HID + 1];
    __shared__ float sW2[HID * ODIM];   // 384 floats = 96 float4
    const int tid = threadIdx.x;
    if (tid < 96) ((float4*)sW2)[tid] = ((const float4*)W2)[tid];
    const int ln = tid & 31;
    const int ng = tid >> 5;
    const int n  = blockIdx.x * 8 + ng;
    float x = 0.f;
    if (n < nNodes) {
        float dg = deg[n];
        if (dg < 1.f) dg = 1.f;
        x = agg1[(size_t)n * HID + ln] / dg + b1[ln];
        x = x > 0.f ? x : 0.f;
    }
    sX[ng][ln] = x;
    __syncthreads();
    if (ln < ODIM && n < nNodes) {
        float acc = 0.f;
        #pragma unroll
        for (int k = 0; k < HID; ++k) acc += sX[ng][k] * sW2[k * ODIM + ln];
        h2[(size_t)n * ODIM + ln] = acc;
    }
}

// agg2[dst] += h2[src].  Rows are 48 B = 3 x float4 (16B-aligned for every n).
__global__ __launch_bounds__(256) void scatter2_kernel(const float* __restrict__ h2,
                                                       const int* __restrict__ src,
                                                       const int* __restrict__ dst,
                                                       float* __restrict__ agg2, int nEdges) {
    int e = blockIdx.x * 256 + threadIdx.x;
    if (e >= nEdges) return;
    int s = src[e], d = dst[e];
    const float4* hr = (const float4*)(h2 + (size_t)s * ODIM);
    float*        ar = agg2 + (size_t)d * ODIM;
    #pragma unroll
    for (int i = 0; i < 3; ++i) {
        float4 v = hr[i];
        atomAddF(ar + i * 4 + 0, v.x);
        atomAddF(ar + i * 4 + 1, v.y);
        atomAddF(ar + i * 4 + 2, v.z);
        atomAddF(ar + i * 4 + 3, v.w);
    }
}

// out = relu(agg2/deg + b2)
__global__ __launch_bounds__(256) void fin2_kernel(const float* __restrict__ agg2,
                                                   const float* __restrict__ deg,
                                                   const float* __restrict__ b2,
                                                   float* __restrict__ out, int nNodes) {
    int idx = blockIdx.x * 256 + threadIdx.x;
    int total = nNodes * ODIM;
    if (idx >= total) return;
    int n = idx / ODIM;
    int o = idx - n * ODIM;
    float dg = deg[n];
    if (dg < 1.f) dg = 1.f;
    float v = agg2[idx] / dg + b2[o];
    out[idx] = v > 0.f ? v : 0.f;
}

extern "C" void kernel_launch(void* const* d_in, const int* in_sizes, int n_in,
                              void* d_out, int out_size, void* d_ws, size_t ws_size,
                              hipStream_t stream) {
    const float* feat = (const float*)d_in[0];
    const int*   src  = (const int*)d_in[1];
    const int*   dst  = (const int*)d_in[2];
    const float* W1   = (const float*)d_in[3];
    const float* b1   = (const float*)d_in[4];
    const float* W2   = (const float*)d_in[5];
    const float* b2   = (const float*)d_in[6];
    float* out = (float*)d_out;

    const int nEdges = in_sizes[1];
    const int nNodes = in_sizes[0] / N_IN;   // 100000

    // workspace layout (floats): h1[N*32] | agg1[N*32] | deg[N] | agg2[N*12]
    float* ws   = (float*)d_ws;
    float* h1   = ws;
    float* agg1 = h1 + (size_t)nNodes * HID;
    float* deg  = agg1 + (size_t)nNodes * HID;
    float* agg2 = deg + nNodes;
    float* h2   = h1;   // h1 dead after scatter1; reuse for h2

    // zero agg1 + deg + agg2 (contiguous region)
    size_t zeroBytes = ((size_t)nNodes * HID + (size_t)nNodes + (size_t)nNodes * ODIM) * sizeof(float);
    hipMemsetAsync(agg1, 0, zeroBytes, stream);

    gemm1_kernel<<<(nNodes + 63) / 64, 256, 0, stream>>>(feat, W1, h1, nNodes);
    scatter1_kernel<<<(nEdges + 255) / 256, 256, 0, stream>>>(h1, src, dst, agg1, deg, nEdges);
    fin1_gemm2_kernel<<<(nNodes + 7) / 8, 256, 0, stream>>>(agg1, deg, b1, W2, h2, nNodes);
    scatter2_kernel<<<(nEdges + 255) / 256, 256, 0, stream>>>(h2, src, dst, agg2, nEdges);
    fin2_kernel<<<(nNodes * ODIM + 255) / 256, 256, 0, stream>>>(agg2, deg, b2, out, nNodes);
}

// Round 2
// 646.834 us; speedup vs baseline: 11.5007x; 11.5007x over previous
//
#include <hip/hip_runtime.h>

#define N_IN   128
#define HID    32
#define ODIM   12

// ---------------- GEMM1: h1[n][32] = feat[n][0:128] @ W1 ----------------
// 64 nodes/block, thread = 2 nodes x 4 outs. LDS-tiled, conflict-free.
__global__ __launch_bounds__(256) void gemm1_kernel(const float* __restrict__ feat,
                                                    const float* __restrict__ W1,
                                                    float* __restrict__ h1, int nNodes) {
    __shared__ float sF[64 * 132];
    __shared__ float sW[N_IN * HID];
    const int tid = threadIdx.x;
    const int nb  = blockIdx.x * 64;

    {
        const float4* Wv  = (const float4*)W1;
        float4*       sWv = (float4*)sW;
        #pragma unroll
        for (int i = 0; i < 4; ++i) sWv[tid + 256 * i] = Wv[tid + 256 * i];
    }
    #pragma unroll
    for (int i = 0; i < 8; ++i) {
        int f   = tid + 256 * i;
        int row = f >> 5;
        int c4  = f & 31;
        int n   = nb + row;
        float4 v = make_float4(0.f, 0.f, 0.f, 0.f);
        if (n < nNodes) v = *(const float4*)(feat + (size_t)n * N_IN + c4 * 4);
        *(float4*)(sF + row * 132 + c4 * 4) = v;
    }
    __syncthreads();

    const int og = tid & 7;
    const int ng = tid >> 3;
    const int o0 = og * 4;
    const float* f0 = sF + ng * 132;
    const float* f1 = sF + (ng + 32) * 132;

    float acc0[4] = {0.f, 0.f, 0.f, 0.f};
    float acc1[4] = {0.f, 0.f, 0.f, 0.f};
    #pragma unroll 8
    for (int k = 0; k < N_IN; k += 4) {
        float4 a0 = *(const float4*)(f0 + k);
        float4 a1 = *(const float4*)(f1 + k);
        const float a0v[4] = {a0.x, a0.y, a0.z, a0.w};
        const float a1v[4] = {a1.x, a1.y, a1.z, a1.w};
        #pragma unroll
        for (int j = 0; j < 4; ++j) {
            float4 w = *(const float4*)(sW + (k + j) * HID + o0);
            acc0[0] += a0v[j] * w.x; acc0[1] += a0v[j] * w.y;
            acc0[2] += a0v[j] * w.z; acc0[3] += a0v[j] * w.w;
            acc1[0] += a1v[j] * w.x; acc1[1] += a1v[j] * w.y;
            acc1[2] += a1v[j] * w.z; acc1[3] += a1v[j] * w.w;
        }
    }
    int n0 = nb + ng, n1 = nb + ng + 32;
    if (n0 < nNodes) *(float4*)(h1 + (size_t)n0 * HID + o0) = make_float4(acc0[0], acc0[1], acc0[2], acc0[3]);
    if (n1 < nNodes) *(float4*)(h1 + (size_t)n1 * HID + o0) = make_float4(acc1[0], acc1[1], acc1[2], acc1[3]);
}

// ---------------- CSR build ----------------
// hist: count[dst]++ (int atomics), 4 edges/thread
__global__ __launch_bounds__(256) void hist_kernel(const int* __restrict__ dst,
                                                   int* __restrict__ count, int nEdges) {
    int t = blockIdx.x * 256 + threadIdx.x;
    int e = t * 4;
    if (e + 3 < nEdges) {
        int4 d = *(const int4*)(dst + e);
        atomicAdd(count + d.x, 1);
        atomicAdd(count + d.y, 1);
        atomicAdd(count + d.z, 1);
        atomicAdd(count + d.w, 1);
    } else {
        for (int i = e; i < nEdges; ++i) atomicAdd(count + dst[i], 1);
    }
}

// scan1: per-block (1024 elems) exclusive scan of count -> cursor, block totals -> bsum
__global__ __launch_bounds__(256) void scan1_kernel(const int* __restrict__ count,
                                                    int* __restrict__ cursor,
                                                    int* __restrict__ bsum, int n) {
    __shared__ int s[256];
    const int tid  = threadIdx.x;
    const int base = blockIdx.x * 1024 + tid * 4;
    int c[4];
    #pragma unroll
    for (int i = 0; i < 4; ++i) c[i] = (base + i < n) ? count[base + i] : 0;
    int tsum = c[0] + c[1] + c[2] + c[3];
    s[tid] = tsum;
    __syncthreads();
    int inc = tsum;
    for (int off = 1; off < 256; off <<= 1) {
        int t = (tid >= off) ? s[tid - off] : 0;
        __syncthreads();
        inc += t;
        s[tid] = inc;
        __syncthreads();
    }
    int excl = inc - tsum;
    int run = excl;
    #pragma unroll
    for (int i = 0; i < 4; ++i) {
        if (base + i < n) cursor[base + i] = run;
        run += c[i];
    }
    if (tid == 255) bsum[blockIdx.x] = inc;   // block total
}

// scan2: single block scans <=128 block totals (exclusive, in place)
__global__ __launch_bounds__(128) void scan2_kernel(int* __restrict__ bsum, int nb) {
    __shared__ int s[128];
    const int tid = threadIdx.x;
    int v = (tid < nb) ? bsum[tid] : 0;
    s[tid] = v;
    __syncthreads();
    int inc = v;
    for (int off = 1; off < 128; off <<= 1) {
        int t = (tid >= off) ? s[tid - off] : 0;
        __syncthreads();
        inc += t;
        s[tid] = inc;
        __syncthreads();
    }
    bsum[tid] = inc - v;   // exclusive
}

// scan3: add block offsets
__global__ __launch_bounds__(256) void scan3_kernel(int* __restrict__ cursor,
                                                    const int* __restrict__ bsum, int n) {
    int i = blockIdx.x * 256 + threadIdx.x;
    if (i < n) cursor[i] += bsum[i >> 10];
}

// place: eidx[atomicAdd(cursor[dst])] = src.  After this, cursor[n] = row end.
__global__ __launch_bounds__(256) void place_kernel(const int* __restrict__ src,
                                                    const int* __restrict__ dst,
                                                    int* __restrict__ cursor,
                                                    int* __restrict__ eidx, int nEdges) {
    int t = blockIdx.x * 256 + threadIdx.x;
    int e = t * 4;
    if (e + 3 < nEdges) {
        int4 s = *(const int4*)(src + e);
        int4 d = *(const int4*)(dst + e);
        eidx[atomicAdd(cursor + d.x, 1)] = s.x;
        eidx[atomicAdd(cursor + d.y, 1)] = s.y;
        eidx[atomicAdd(cursor + d.z, 1)] = s.z;
        eidx[atomicAdd(cursor + d.w, 1)] = s.w;
    } else {
        for (int i = e; i < nEdges; ++i) eidx[atomicAdd(cursor + dst[i], 1)] = src[i];
    }
}

// ---------------- agg1 + fin1 + gemm2 fused ----------------
// 8 nodes/block, 32 lanes/node. Gather-sum h1 rows, x=relu(sum/deg+b1),
// h2 = x @ W2 via width-32 shuffles.
__global__ __launch_bounds__(256) void agg1_kernel(const float* __restrict__ h1,
                                                   const int* __restrict__ count,
                                                   const int* __restrict__ cursor,
                                                   const int* __restrict__ eidx,
                                                   const float* __restrict__ b1,
                                                   const float* __restrict__ W2,
                                                   float* __restrict__ h2, int nNodes) {
    __shared__ float sW2[HID * ODIM];   // 384
    const int tid = threadIdx.x;
    if (tid < 96) ((float4*)sW2)[tid] = ((const float4*)W2)[tid];
    __syncthreads();

    const int n = blockIdx.x * 8 + (tid >> 5);
    const int c = tid & 31;
    if (n >= nNodes) return;

    const int cnt = count[n];
    const int end = cursor[n];        // after place: row end
    const int beg = end - cnt;

    float s0 = 0.f, s1 = 0.f, s2 = 0.f, s3 = 0.f;
    int i = beg;
    for (; i + 4 <= end; i += 4) {
        int e0 = eidx[i], e1 = eidx[i + 1], e2 = eidx[i + 2], e3 = eidx[i + 3];
        s0 += h1[(size_t)e0 * HID + c];
        s1 += h1[(size_t)e1 * HID + c];
        s2 += h1[(size_t)e2 * HID + c];
        s3 += h1[(size_t)e3 * HID + c];
    }
    for (; i < end; ++i) s0 += h1[(size_t)eidx[i] * HID + c];
    float sum = (s0 + s1) + (s2 + s3);

    float dg = (float)(cnt < 1 ? 1 : cnt);
    float x = sum / dg + b1[c];
    x = x > 0.f ? x : 0.f;

    // h2[n][c] for c<12 : sum_k x_k * W2[k][c]
    const int col = (c < ODIM) ? c : 0;
    float acc = 0.f;
    #pragma unroll
    for (int k = 0; k < HID; ++k) {
        float xk = __shfl(x, k, 32);
        acc += xk * sW2[k * ODIM + col];
    }
    if (c < ODIM) h2[(size_t)n * ODIM + c] = acc;
}

// ---------------- agg2 + fin2 fused ----------------
// 16 nodes/block, 16 lanes/node (12 active cols). out = relu(sum/deg + b2).
__global__ __launch_bounds__(256) void agg2_kernel(const float* __restrict__ h2,
                                                   const int* __restrict__ count,
                                                   const int* __restrict__ cursor,
                                                   const int* __restrict__ eidx,
                                                   const float* __restrict__ b2,
                                                   float* __restrict__ out, int nNodes) {
    const int tid = threadIdx.x;
    const int n = blockIdx.x * 16 + (tid >> 4);
    const int c = tid & 15;
    if (n >= nNodes) return;

    const int cnt = count[n];
    const int end = cursor[n];
    const int beg = end - cnt;
    const int col = (c < ODIM) ? c : 0;

    float s0 = 0.f, s1 = 0.f;
    int i = beg;
    for (; i + 2 <= end; i += 2) {
        int e0 = eidx[i], e1 = eidx[i + 1];
        s0 += h2[(size_t)e0 * ODIM + col];
        s1 += h2[(size_t)e1 * ODIM + col];
    }
    for (; i < end; ++i) s0 += h2[(size_t)eidx[i] * ODIM + col];
    float sum = s0 + s1;

    float dg = (float)(cnt < 1 ? 1 : cnt);
    float v = sum / dg + b2[col];
    v = v > 0.f ? v : 0.f;
    if (c < ODIM) out[(size_t)n * ODIM + c] = v;
}

extern "C" void kernel_launch(void* const* d_in, const int* in_sizes, int n_in,
                              void* d_out, int out_size, void* d_ws, size_t ws_size,
                              hipStream_t stream) {
    const float* feat = (const float*)d_in[0];
    const int*   src  = (const int*)d_in[1];
    const int*   dst  = (const int*)d_in[2];
    const float* W1   = (const float*)d_in[3];
    const float* b1   = (const float*)d_in[4];
    const float* W2   = (const float*)d_in[5];
    const float* b2   = (const float*)d_in[6];
    float* out = (float*)d_out;

    const int nEdges = in_sizes[1];
    const int nNodes = in_sizes[0] / N_IN;   // 100000

    // workspace layout: h1[N*32] f | h2[N*12] f | count[N] i | cursor[N] i | bsum[128] i | eidx[E] i
    float* h1     = (float*)d_ws;
    float* h2     = h1 + (size_t)nNodes * HID;
    int*   count  = (int*)(h2 + (size_t)nNodes * ODIM);
    int*   cursor = count + nNodes;
    int*   bsum   = cursor + nNodes;
    int*   eidx   = bsum + 128;

    // zero count (cursor/bsum zeroed too, contiguous — harmless, they get overwritten)
    hipMemsetAsync(count, 0, ((size_t)nNodes * 2 + 128) * sizeof(int), stream);

    gemm1_kernel<<<(nNodes + 63) / 64, 256, 0, stream>>>(feat, W1, h1, nNodes);
    hist_kernel<<<((nEdges + 3) / 4 + 255) / 256, 256, 0, stream>>>(dst, count, nEdges);

    const int nScanBlocks = (nNodes + 1023) / 1024;   // 98 <= 128
    scan1_kernel<<<nScanBlocks, 256, 0, stream>>>(count, cursor, bsum, nNodes);
    scan2_kernel<<<1, 128, 0, stream>>>(bsum, nScanBlocks);
    scan3_kernel<<<(nNodes + 255) / 256, 256, 0, stream>>>(cursor, bsum, nNodes);

    place_kernel<<<((nEdges + 3) / 4 + 255) / 256, 256, 0, stream>>>(src, dst, cursor, eidx, nEdges);

    agg1_kernel<<<(nNodes + 7) / 8, 256, 0, stream>>>(h1, count, cursor, eidx, b1, W2, h2, nNodes);
    agg2_kernel<<<(nNodes + 15) / 16, 256, 0, stream>>>(h2, count, cursor, eidx, b2, out, nNodes);
}